// Round 1
// baseline (584.586 us; speedup 1.0000x reference)
//
#include <hip/hip_runtime.h>
#include <float.h>
#include <math.h>

#define NB 2
#define MQ 16384
#define NQ (NB*MQ)          // 32768 queries
#define PP 5023
#define KNN 4
#define HPX 256
#define HWSZ (HPX*HPX)      // 65536

// output layout (floats): densities[NQ], rgb[NQ*32], dist[NQ*4]
#define OUT_RGB_OFF  ((size_t)NQ)
#define OUT_DIST_OFF ((size_t)NQ + (size_t)NQ*32)

// workspace layout (bytes)
#define WS_SUMS_OFF ((size_t)NQ*KNN*4)   // after idx region (NQ*4 ints)
#define WS_TEX_OFF  ((size_t)1<<20)

// ------------------------------------------------------------------
// texture transpose: [n3][32][HW] -> [n3][HW][32]
__global__ __launch_bounds__(256) void k_transpose(const float* __restrict__ src,
                                                   float* __restrict__ dst) {
    const int tid = threadIdx.x;
    const int b = blockIdx.x;            // 6*256 blocks
    const int n3 = b >> 8;
    const int hw = ((b & 255) << 8) + tid;
    const float* s = src + (size_t)n3 * 32 * HWSZ + hw;
    float v[32];
#pragma unroll
    for (int c = 0; c < 32; ++c) v[c] = s[(size_t)c * HWSZ];
    float4* d = (float4*)(dst + ((size_t)n3 * HWSZ + hw) * 32);
#pragma unroll
    for (int c = 0; c < 8; ++c) d[c] = make_float4(v[4*c], v[4*c+1], v[4*c+2], v[4*c+3]);
}

// ------------------------------------------------------------------
// KNN: wave-per-query, lane-split over P, butterfly merge
__global__ __launch_bounds__(256) void k_knn(const float* __restrict__ coords,
                                             const float* __restrict__ pts,
                                             float* __restrict__ odist,
                                             int* __restrict__ oidx) {
    const int lane = threadIdx.x & 63;
    const int q = blockIdx.x * 4 + (threadIdx.x >> 6);
    const int n = q >> 14;
    const float cx = coords[q*3+0], cy = coords[q*3+1], cz = coords[q*3+2];
    const float cc = fmaf(cx, cx, fmaf(cy, cy, cz*cz));

    float bd[4]; int bi[4];
#pragma unroll
    for (int j = 0; j < 4; ++j) { bd[j] = FLT_MAX; bi[j] = 0x7fffffff; }

    const float* pb = pts + (size_t)n * PP * 3;
    for (int p = lane; p < PP; p += 64) {
        float px = pb[p*3+0], py = pb[p*3+1], pz = pb[p*3+2];
        float pp2 = fmaf(px, px, fmaf(py, py, pz*pz));
        float dt  = fmaf(cx, px, fmaf(cy, py, cz*pz));
        float dd  = fmaf(-2.0f, dt, cc + pp2);
        if (dd < bd[3]) {
            bd[3] = dd; bi[3] = p;
            if (bd[3] < bd[2]) { float td=bd[2]; bd[2]=bd[3]; bd[3]=td; int ti=bi[2]; bi[2]=bi[3]; bi[3]=ti; }
            if (bd[2] < bd[1]) { float td=bd[1]; bd[1]=bd[2]; bd[2]=td; int ti=bi[1]; bi[1]=bi[2]; bi[2]=ti; }
            if (bd[1] < bd[0]) { float td=bd[0]; bd[0]=bd[1]; bd[1]=td; int ti=bi[0]; bi[0]=bi[1]; bi[1]=ti; }
        }
    }

    // butterfly all-reduce merge of sorted 4-lists (tie-break on index)
#pragma unroll
    for (int mask = 1; mask < 64; mask <<= 1) {
        float od[4]; int oi[4];
#pragma unroll
        for (int j = 0; j < 4; ++j) { od[j] = __shfl_xor(bd[j], mask); oi[j] = __shfl_xor(bi[j], mask); }
        float e[4]; int ei[4];
#pragma unroll
        for (int j = 0; j < 4; ++j) {
            float ad = bd[j], xd = od[3-j];
            int   ai = bi[j], xi = oi[3-j];
            bool ta = (ad < xd) || (ad == xd && ai < xi);
            e[j] = ta ? ad : xd; ei[j] = ta ? ai : xi;
        }
#define CE(a,b) { bool sw = (e[b] < e[a]) || (e[b] == e[a] && ei[b] < ei[a]); \
                  if (sw) { float td=e[a]; e[a]=e[b]; e[b]=td; int ti=ei[a]; ei[a]=ei[b]; ei[b]=ti; } }
        CE(0,2) CE(1,3) CE(0,1) CE(2,3)
#undef CE
#pragma unroll
        for (int j = 0; j < 4; ++j) { bd[j] = e[j]; bi[j] = ei[j]; }
    }

    if (lane == 0) {
        *(float4*)(odist + (size_t)q*4) = make_float4(bd[0], bd[1], bd[2], bd[3]);
        *(int4*)(oidx + (size_t)q*4)    = make_int4(bi[0], bi[1], bi[2], bi[3]);
    }
}

// ------------------------------------------------------------------
// per-(n,k) sum over m of 1/dist (deterministic)
__global__ __launch_bounds__(256) void k_sums(const float* __restrict__ dist,
                                              float* __restrict__ sums) {
    const int b = blockIdx.x;            // n*4+k, 8 blocks
    const int n = b >> 2, k = b & 3;
    float s = 0.f;
    for (int m = threadIdx.x; m < MQ; m += 256)
        s += 1.0f / dist[((size_t)n * MQ + m) * 4 + k];
    __shared__ float red[256];
    red[threadIdx.x] = s;
    __syncthreads();
    for (int off = 128; off > 0; off >>= 1) {
        if (threadIdx.x < off) red[threadIdx.x] += red[threadIdx.x + off];
        __syncthreads();
    }
    if (threadIdx.x == 0) sums[b] = red[0];
}

// ------------------------------------------------------------------
template<int DIN, int DOUT, int TILE>
__device__ __forceinline__ void gemv_tile(const float (&x)[DIN],
                                          const float* __restrict__ W,
                                          const float* __restrict__ bias,
                                          int j0, float (&acc)[TILE]) {
#pragma unroll
    for (int u = 0; u < TILE; ++u) acc[u] = bias[j0 + u];
#pragma unroll
    for (int i = 0; i < DIN; ++i) {
        const float xv = x[i];
        const float* wr = W + i * DOUT + j0;
#pragma unroll
        for (int u = 0; u < TILE; ++u) acc[u] = fmaf(xv, wr[u], acc[u]);
    }
}

// ------------------------------------------------------------------
// main fused kernel: block = 64 queries, 4 waves j-split every layer
__global__ __launch_bounds__(256, 2) void k_main(
    const float* __restrict__ coords, const float* __restrict__ dirs,
    const float* __restrict__ pts, const float* __restrict__ tex_raw,
    const float* __restrict__ tex_t, const float* __restrict__ emb,
    const float* __restrict__ pw1, const float* __restrict__ pb1,
    const float* __restrict__ pw2, const float* __restrict__ pb2,
    const float* __restrict__ fw1, const float* __restrict__ fb1,
    const float* __restrict__ fw2, const float* __restrict__ fb2,
    const float* __restrict__ fw3, const float* __restrict__ fb3,
    const float* __restrict__ dw,  const float* __restrict__ db,
    const float* __restrict__ rw1, const float* __restrict__ rb1,
    const float* __restrict__ rw2, const float* __restrict__ rb2,
    const int* __restrict__ idxbuf, const float* __restrict__ distbuf,
    const float* __restrict__ sums, float* __restrict__ out, int use_tex_t)
{
    __shared__ float A[128 * 64];
    __shared__ float B[128 * 64];
    const int tid  = threadIdx.x;
    const int lane = tid & 63;
    const int wv   = __builtin_amdgcn_readfirstlane(tid >> 6);
    const int q0   = blockIdx.x * 64;
    const int n    = q0 >> 14;

    // ---------- phase 1: triplane sampling -> A rows 0..31 (mean/3) ----------
    {
        const int m = lane, g = wv;   // g: channel group of 8
        const int q = q0 + m;
        const float cx = coords[q*3+0], cy = coords[q*3+1], cz = coords[q*3+2];
        float acc[8];
#pragma unroll
        for (int u = 0; u < 8; ++u) acc[u] = 0.f;
#pragma unroll
        for (int pl = 0; pl < 3; ++pl) {
            float gx = (pl == 2) ? cz : cx;
            float gy = (pl == 0) ? cy : ((pl == 1) ? cz : cx);
            float x = (gx + 1.f) * 128.f - 0.5f;
            float y = (gy + 1.f) * 128.f - 0.5f;
            float x0f = floorf(x), y0f = floorf(y);
            float wx1 = x - x0f, wy1 = y - y0f;
            float wx0 = 1.f - wx1, wy0 = 1.f - wy1;
            int x0 = (int)x0f, y0 = (int)y0f;
            int n3 = n * 3 + pl;
            int  xs[4] = { x0, x0+1, x0,   x0+1 };
            int  ys[4] = { y0, y0,   y0+1, y0+1 };
            float wt[4] = { wx0*wy0, wx1*wy0, wx0*wy1, wx1*wy1 };
#pragma unroll
            for (int c = 0; c < 4; ++c) {
                int xi = xs[c], yi = ys[c];
                if (xi >= 0 && xi < HPX && yi >= 0 && yi < HPX) {
                    float wgt = wt[c];
                    if (use_tex_t) {
                        const float4* p4 = (const float4*)(tex_t +
                            (((size_t)n3 * HWSZ + (size_t)yi * HPX + xi) * 32 + g * 8));
                        float4 a = p4[0], b = p4[1];
                        acc[0] = fmaf(wgt, a.x, acc[0]); acc[1] = fmaf(wgt, a.y, acc[1]);
                        acc[2] = fmaf(wgt, a.z, acc[2]); acc[3] = fmaf(wgt, a.w, acc[3]);
                        acc[4] = fmaf(wgt, b.x, acc[4]); acc[5] = fmaf(wgt, b.y, acc[5]);
                        acc[6] = fmaf(wgt, b.z, acc[6]); acc[7] = fmaf(wgt, b.w, acc[7]);
                    } else {
                        size_t base = ((size_t)(n3 * 32 + g * 8)) * HWSZ + (size_t)yi * HPX + xi;
#pragma unroll
                        for (int u = 0; u < 8; ++u)
                            acc[u] = fmaf(wgt, tex_raw[base + (size_t)u * HWSZ], acc[u]);
                    }
                }
            }
        }
#pragma unroll
        for (int u = 0; u < 8; ++u) A[(g*8 + u) * 64 + m] = acc[u] * (1.f / 3.f);
    }

    // ---------- phase 2: per-neighbor point MLP, k sequential ----------
    float pts_acc[8];
#pragma unroll
    for (int u = 0; u < 8; ++u) pts_acc[u] = 0.f;

#pragma unroll 1
    for (int k = 0; k < KNN; ++k) {
        // k.a: build x59 into B rows 64..122 (col = m)
        {
            const int m = lane, g = wv;
            const int q = q0 + m;
            const int id = idxbuf[(size_t)q*4 + k];
            const float4* e4 = (const float4*)(emb + (size_t)id * 32 + g * 8);
            float4 ea = e4[0], eb = e4[1];
            B[(64 + g*8 + 0)*64 + m] = ea.x; B[(64 + g*8 + 1)*64 + m] = ea.y;
            B[(64 + g*8 + 2)*64 + m] = ea.z; B[(64 + g*8 + 3)*64 + m] = ea.w;
            B[(64 + g*8 + 4)*64 + m] = eb.x; B[(64 + g*8 + 5)*64 + m] = eb.y;
            B[(64 + g*8 + 6)*64 + m] = eb.z; B[(64 + g*8 + 7)*64 + m] = eb.w;

            const float cx = coords[q*3+0], cy = coords[q*3+1], cz = coords[q*3+2];
            const float nx = pts[((size_t)n*PP + id)*3 + 0];
            const float ny = pts[((size_t)n*PP + id)*3 + 1];
            const float nz = pts[((size_t)n*PP + id)*3 + 2];
            float rx = cx - nx, ry = cy - ny, rz = cz - nz;
            float nrm = sqrtf(fmaf(rx, rx, fmaf(ry, ry, rz*rz)));
            float inv = 1.f / fmaxf(nrm, 1e-12f);
            rx *= inv; ry *= inv; rz *= inv;
            float hv[27];
#pragma unroll
            for (int c3 = 0; c3 < 3; ++c3) {
                float rv = (c3 == 0) ? rx : ((c3 == 1) ? ry : rz);
                float f = 1.f;
#pragma unroll
                for (int fr = 0; fr < 4; ++fr) {
                    float e = rv * f;
                    hv[c3*4 + fr] = sinf(e);
                    hv[12 + c3*4 + fr] = cosf(e);
                    f *= 2.f;
                }
            }
            hv[24] = rx; hv[25] = ry; hv[26] = rz;
            const int h0 = g * 7;
            const int h1 = (h0 + 7 < 27) ? (h0 + 7) : 27;
#pragma unroll
            for (int h = 0; h < 27; ++h)
                if (h >= h0 && h < h1) B[(96 + h)*64 + m] = hv[h];
        }
        __syncthreads();
        // k.b: p1 59->64 relu, wave wv -> j0 = wv*16
        {
            float x[59];
#pragma unroll
            for (int i = 0; i < 59; ++i) x[i] = B[(64 + i)*64 + lane];
            float acc[16];
            gemv_tile<59, 64, 16>(x, pw1, pb1, wv * 16, acc);
#pragma unroll
            for (int u = 0; u < 16; ++u) B[(wv*16 + u)*64 + lane] = fmaxf(acc[u], 0.f);
        }
        __syncthreads();
        // k.c: p2 64->32 (no relu), accumulate w_k * h2
        {
            float x[64];
#pragma unroll
            for (int i = 0; i < 64; ++i) x[i] = B[i*64 + lane];
            float acc[8];
            gemv_tile<64, 32, 8>(x, pw2, pb2, wv * 8, acc);
            const int q = q0 + lane;
            float dist = distbuf[(size_t)q*4 + k];
            float wk = (1.0f / dist) / sums[n*4 + k];
#pragma unroll
            for (int u = 0; u < 8; ++u) pts_acc[u] = fmaf(wk, acc[u], pts_acc[u]);
        }
        __syncthreads();
    }
#pragma unroll
    for (int u = 0; u < 8; ++u) A[(32 + wv*8 + u)*64 + lane] = pts_acc[u];
    __syncthreads();

    // ---------- dense stack ----------
    // fw1: 64 -> 128, relu, A -> B
    {
        float x[64];
#pragma unroll
        for (int i = 0; i < 64; ++i) x[i] = A[i*64 + lane];
#pragma unroll 1
        for (int t = 0; t < 2; ++t) {
            int j0 = wv*32 + t*16;
            float acc[16];
            gemv_tile<64, 128, 16>(x, fw1, fb1, j0, acc);
#pragma unroll
            for (int u = 0; u < 16; ++u) B[(j0 + u)*64 + lane] = fmaxf(acc[u], 0.f);
        }
    }
    __syncthreads();
    // fw2: 128 -> 128, relu, B -> A
    {
        float x[128];
#pragma unroll
        for (int i = 0; i < 128; ++i) x[i] = B[i*64 + lane];
#pragma unroll 1
        for (int t = 0; t < 2; ++t) {
            int j0 = wv*32 + t*16;
            float acc[16];
            gemv_tile<128, 128, 16>(x, fw2, fb2, j0, acc);
#pragma unroll
            for (int u = 0; u < 16; ++u) A[(j0 + u)*64 + lane] = fmaxf(acc[u], 0.f);
        }
    }
    __syncthreads();
    // fw3: 128 -> 128, no relu, A -> B
    {
        float x[128];
#pragma unroll
        for (int i = 0; i < 128; ++i) x[i] = A[i*64 + lane];
#pragma unroll 1
        for (int t = 0; t < 2; ++t) {
            int j0 = wv*32 + t*16;
            float acc[16];
            gemv_tile<128, 128, 16>(x, fw3, fb3, j0, acc);
#pragma unroll
            for (int u = 0; u < 16; ++u) B[(j0 + u)*64 + lane] = acc[u];
        }
    }
    __syncthreads();
    // head: density + rgb (rw1 155->64 relu)
    {
        float x[155];
#pragma unroll
        for (int i = 0; i < 128; ++i) x[i] = B[i*64 + lane];
        const int q = q0 + lane;
        if (wv == 0) {
            float z = db[0];
#pragma unroll
            for (int i = 0; i < 128; ++i) z = fmaf(x[i], dw[i], z);
            const float cx = coords[q*3+0], cy = coords[q*3+1], cz = coords[q*3+2];
            float selv = (cx > -1.f && cx < 1.f && cy > -1.f && cy < 1.f &&
                          cz > -1.f && cz < 1.f) ? 1.f : 0.f;
            float t10 = 10.f * z;
            float sp = (t10 > 20.f) ? t10 : log1pf(expf(t10));
            float raw = sp * 0.1f * selv;
            out[q] = 1.f - expf(-raw);
        }
        // ray harmonic into x[128..154]
        float dx = dirs[q*3+0], dy = dirs[q*3+1], dz = dirs[q*3+2];
        float dn = sqrtf(fmaf(dx, dx, fmaf(dy, dy, dz*dz)));
        float inv = 1.f / fmaxf(dn, 1e-12f);
        dx *= inv; dy *= inv; dz *= inv;
#pragma unroll
        for (int c3 = 0; c3 < 3; ++c3) {
            float rv = (c3 == 0) ? dx : ((c3 == 1) ? dy : dz);
            float f = 1.f;
#pragma unroll
            for (int fr = 0; fr < 4; ++fr) {
                float e = rv * f;
                x[128 + c3*4 + fr] = sinf(e);
                x[140 + c3*4 + fr] = cosf(e);
                f *= 2.f;
            }
        }
        x[152] = dx; x[153] = dy; x[154] = dz;
        float acc[16];
        gemv_tile<155, 64, 16>(x, rw1, rb1, wv * 16, acc);
#pragma unroll
        for (int u = 0; u < 16; ++u) A[(wv*16 + u)*64 + lane] = fmaxf(acc[u], 0.f);
    }
    __syncthreads();
    // rw2: 64 -> 32, sigmoid on first 3
    {
        float x[64];
#pragma unroll
        for (int i = 0; i < 64; ++i) x[i] = A[i*64 + lane];
        float acc[8];
        gemv_tile<64, 32, 8>(x, rw2, rb2, wv * 8, acc);
        const int q = q0 + lane;
#pragma unroll
        for (int u = 0; u < 8; ++u) {
            int j = wv*8 + u;
            float v = acc[u];
            if (j < 3) v = 1.002f * (1.f / (1.f + expf(-v))) - 0.001f;
            out[OUT_RGB_OFF + (size_t)q*32 + j] = v;
        }
    }
}

// ------------------------------------------------------------------
extern "C" void kernel_launch(void* const* d_in, const int* in_sizes, int n_in,
                              void* d_out, int out_size, void* d_ws, size_t ws_size,
                              hipStream_t stream) {
    (void)in_sizes; (void)n_in; (void)out_size;
    const float* coords = (const float*)d_in[0];
    const float* dirs   = (const float*)d_in[1];
    const float* pts    = (const float*)d_in[2];
    const float* tex    = (const float*)d_in[3];
    const float* emb    = (const float*)d_in[4];
    const float* pw1 = (const float*)d_in[5];  const float* pb1 = (const float*)d_in[6];
    const float* pw2 = (const float*)d_in[7];  const float* pb2 = (const float*)d_in[8];
    const float* fw1 = (const float*)d_in[9];  const float* fb1 = (const float*)d_in[10];
    const float* fw2 = (const float*)d_in[11]; const float* fb2 = (const float*)d_in[12];
    const float* fw3 = (const float*)d_in[13]; const float* fb3 = (const float*)d_in[14];
    const float* dw  = (const float*)d_in[15]; const float* db  = (const float*)d_in[16];
    const float* rw1 = (const float*)d_in[17]; const float* rb1 = (const float*)d_in[18];
    const float* rw2 = (const float*)d_in[19]; const float* rb2 = (const float*)d_in[20];

    float* out    = (float*)d_out;
    int*   wsidx  = (int*)d_ws;
    float* wssums = (float*)((char*)d_ws + WS_SUMS_OFF);
    float* wstex  = (float*)((char*)d_ws + WS_TEX_OFF);

    const size_t need_tex = WS_TEX_OFF + (size_t)6 * HWSZ * 32 * 4;
    const int use_t = (ws_size >= need_tex) ? 1 : 0;

    if (use_t) k_transpose<<<6 * 256, 256, 0, stream>>>(tex, wstex);
    k_knn<<<NQ / 4, 256, 0, stream>>>(coords, pts, out + OUT_DIST_OFF, wsidx);
    k_sums<<<8, 256, 0, stream>>>(out + OUT_DIST_OFF, wssums);
    k_main<<<NQ / 64, 256, 0, stream>>>(coords, dirs, pts, tex, wstex, emb,
                                        pw1, pb1, pw2, pb2,
                                        fw1, fb1, fw2, fb2, fw3, fb3,
                                        dw, db, rw1, rb1, rw2, rb2,
                                        wsidx, out + OUT_DIST_OFF, wssums, out, use_t);
}

// Round 2
// 488.326 us; speedup vs baseline: 1.1971x; 1.1971x over previous
//
#include <hip/hip_runtime.h>
#include <float.h>
#include <math.h>

#define NB 2
#define MQ 16384
#define NQ (NB*MQ)          // 32768 queries
#define PP 5023
#define KNN 4
#define HPX 256
#define HWSZ (HPX*HPX)      // 65536

// output layout (floats): densities[NQ], rgb[NQ*32], dist[NQ*4]
#define OUT_RGB_OFF  ((size_t)NQ)
#define OUT_DIST_OFF ((size_t)NQ + (size_t)NQ*32)

// workspace layout (bytes)
#define WS_SUMS_OFF ((size_t)NQ*KNN*4)   // after idx region (NQ*4 ints)
#define WS_TEX_OFF  ((size_t)1<<20)

// ------------------------------------------------------------------
// texture transpose: [n3][32][HW] -> [n3][HW][32]
__global__ __launch_bounds__(256) void k_transpose(const float* __restrict__ src,
                                                   float* __restrict__ dst) {
    const int tid = threadIdx.x;
    const int b = blockIdx.x;            // 6*256 blocks
    const int n3 = b >> 8;
    const int hw = ((b & 255) << 8) + tid;
    const float* s = src + (size_t)n3 * 32 * HWSZ + hw;
    float v[32];
#pragma unroll
    for (int c = 0; c < 32; ++c) v[c] = s[(size_t)c * HWSZ];
    float4* d = (float4*)(dst + ((size_t)n3 * HWSZ + hw) * 32);
#pragma unroll
    for (int c = 0; c < 8; ++c) d[c] = make_float4(v[4*c], v[4*c+1], v[4*c+2], v[4*c+3]);
}

// ------------------------------------------------------------------
// KNN v2: 16 lanes per query, LDS-staged point chunks, branchless insert
#define KCH 1024
__global__ __launch_bounds__(256) void k_knn(const float* __restrict__ coords,
                                             const float* __restrict__ pts,
                                             float* __restrict__ odist,
                                             int* __restrict__ oidx) {
    __shared__ float4 sp[KCH];
    const int tid = threadIdx.x;
    const int l = tid & 15;
    const int q = blockIdx.x * 16 + (tid >> 4);   // 2048 blocks
    const int n = q >> 14;
    const float cx = coords[q*3+0], cy = coords[q*3+1], cz = coords[q*3+2];
    const float cc = fmaf(cx, cx, fmaf(cy, cy, cz*cz));

    float bd0 = FLT_MAX, bd1 = FLT_MAX, bd2 = FLT_MAX, bd3 = FLT_MAX;
    int   bi0 = 0x7fffffff, bi1 = 0x7fffffff, bi2 = 0x7fffffff, bi3 = 0x7fffffff;

    const float* pb = pts + (size_t)n * PP * 3;
#pragma unroll 1
    for (int c0 = 0; c0 < PP; c0 += KCH) {
        const int cnt = (PP - c0 < KCH) ? (PP - c0) : KCH;
        __syncthreads();
        for (int j = tid; j < cnt; j += 256) {
            const float* p3 = pb + (size_t)(c0 + j) * 3;
            float px = p3[0], py = p3[1], pz = p3[2];
            sp[j] = make_float4(px, py, pz, fmaf(px, px, fmaf(py, py, pz*pz)));
        }
        __syncthreads();
#pragma unroll 4
        for (int j = l; j < cnt; j += 16) {
            float4 P = sp[j];
            float dt = fmaf(cx, P.x, fmaf(cy, P.y, cz * P.z));
            float dd = fmaf(-2.0f, dt, cc + P.w);
            int p = c0 + j;
            bool lt3 = dd < bd3, lt2 = dd < bd2, lt1 = dd < bd1, lt0 = dd < bd0;
            bd3 = lt3 ? (lt2 ? bd2 : dd) : bd3;  bi3 = lt3 ? (lt2 ? bi2 : p) : bi3;
            bd2 = lt2 ? (lt1 ? bd1 : dd) : bd2;  bi2 = lt2 ? (lt1 ? bi1 : p) : bi2;
            bd1 = lt1 ? (lt0 ? bd0 : dd) : bd1;  bi1 = lt1 ? (lt0 ? bi0 : p) : bi1;
            bd0 = lt0 ? dd : bd0;                bi0 = lt0 ? p : bi0;
        }
    }

    float bd[4] = { bd0, bd1, bd2, bd3 };
    int   bi[4] = { bi0, bi1, bi2, bi3 };
    // butterfly merge of sorted 4-lists within the 16-lane group (tie-break on index)
#pragma unroll
    for (int mask = 1; mask < 16; mask <<= 1) {
        float od[4]; int oi[4];
#pragma unroll
        for (int j = 0; j < 4; ++j) { od[j] = __shfl_xor(bd[j], mask); oi[j] = __shfl_xor(bi[j], mask); }
        float e[4]; int ei[4];
#pragma unroll
        for (int j = 0; j < 4; ++j) {
            float ad = bd[j], xd = od[3-j];
            int   ai = bi[j], xi = oi[3-j];
            bool ta = (ad < xd) || (ad == xd && ai < xi);
            e[j] = ta ? ad : xd; ei[j] = ta ? ai : xi;
        }
#define CE(a,b) { bool sw = (e[b] < e[a]) || (e[b] == e[a] && ei[b] < ei[a]); \
                  if (sw) { float td=e[a]; e[a]=e[b]; e[b]=td; int ti=ei[a]; ei[a]=ei[b]; ei[b]=ti; } }
        CE(0,2) CE(1,3) CE(0,1) CE(2,3)
#undef CE
#pragma unroll
        for (int j = 0; j < 4; ++j) { bd[j] = e[j]; bi[j] = ei[j]; }
    }

    if (l == 0) {
        *(float4*)(odist + (size_t)q*4) = make_float4(bd[0], bd[1], bd[2], bd[3]);
        *(int4*)(oidx + (size_t)q*4)    = make_int4(bi[0], bi[1], bi[2], bi[3]);
    }
}

// ------------------------------------------------------------------
// per-(n,k) sum over m of 1/dist (deterministic)
__global__ __launch_bounds__(1024) void k_sums(const float* __restrict__ dist,
                                               float* __restrict__ sums) {
    const int b = blockIdx.x;            // n*4+k, 8 blocks
    const int n = b >> 2, k = b & 3;
    float s = 0.f;
    for (int m = threadIdx.x; m < MQ; m += 1024)
        s += 1.0f / dist[((size_t)n * MQ + m) * 4 + k];
    __shared__ float red[1024];
    red[threadIdx.x] = s;
    __syncthreads();
    for (int off = 512; off > 0; off >>= 1) {
        if (threadIdx.x < off) red[threadIdx.x] += red[threadIdx.x + off];
        __syncthreads();
    }
    if (threadIdx.x == 0) sums[b] = red[0];
}

// ------------------------------------------------------------------
template<int DIN, int DOUT, int TILE>
__device__ __forceinline__ void gemv_tile(const float (&x)[DIN],
                                          const float* __restrict__ W,
                                          const float* __restrict__ bias,
                                          int j0, float (&acc)[TILE]) {
#pragma unroll
    for (int u = 0; u < TILE; ++u) acc[u] = bias[j0 + u];
#pragma unroll
    for (int i = 0; i < DIN; ++i) {
        const float xv = x[i];
        const float* wr = W + i * DOUT + j0;
#pragma unroll
        for (int u = 0; u < TILE; ++u) acc[u] = fmaf(xv, wr[u], acc[u]);
    }
}

// ------------------------------------------------------------------
// main fused kernel v2: block = 64 queries, 8 waves j-split every layer
// (same 64 KB LDS as v1 but 8 waves/block -> 2 blocks/CU = 16 waves/CU)
__global__ __launch_bounds__(512, 4) void k_main(
    const float* __restrict__ coords, const float* __restrict__ dirs,
    const float* __restrict__ pts, const float* __restrict__ tex_raw,
    const float* __restrict__ tex_t, const float* __restrict__ emb,
    const float* __restrict__ pw1, const float* __restrict__ pb1,
    const float* __restrict__ pw2, const float* __restrict__ pb2,
    const float* __restrict__ fw1, const float* __restrict__ fb1,
    const float* __restrict__ fw2, const float* __restrict__ fb2,
    const float* __restrict__ fw3, const float* __restrict__ fb3,
    const float* __restrict__ dw,  const float* __restrict__ db,
    const float* __restrict__ rw1, const float* __restrict__ rb1,
    const float* __restrict__ rw2, const float* __restrict__ rb2,
    const int* __restrict__ idxbuf, const float* __restrict__ distbuf,
    const float* __restrict__ sums, float* __restrict__ out, int use_tex_t)
{
    __shared__ float A[128 * 64];
    __shared__ float B[128 * 64];
    const int tid  = threadIdx.x;
    const int lane = tid & 63;
    const int wv   = __builtin_amdgcn_readfirstlane(tid >> 6);   // 0..7
    const int q0   = blockIdx.x * 64;
    const int n    = q0 >> 14;

    // ---------- phase 1: triplane sampling -> A rows 0..31 (mean/3) ----------
    {
        const int m = lane, g = wv;   // g: channel group of 4
        const int q = q0 + m;
        const float cx = coords[q*3+0], cy = coords[q*3+1], cz = coords[q*3+2];
        float acc[4];
#pragma unroll
        for (int u = 0; u < 4; ++u) acc[u] = 0.f;
#pragma unroll
        for (int pl = 0; pl < 3; ++pl) {
            float gx = (pl == 2) ? cz : cx;
            float gy = (pl == 0) ? cy : ((pl == 1) ? cz : cx);
            float x = (gx + 1.f) * 128.f - 0.5f;
            float y = (gy + 1.f) * 128.f - 0.5f;
            float x0f = floorf(x), y0f = floorf(y);
            float wx1 = x - x0f, wy1 = y - y0f;
            float wx0 = 1.f - wx1, wy0 = 1.f - wy1;
            int x0 = (int)x0f, y0 = (int)y0f;
            int n3 = n * 3 + pl;
            int  xs[4] = { x0, x0+1, x0,   x0+1 };
            int  ys[4] = { y0, y0,   y0+1, y0+1 };
            float wt[4] = { wx0*wy0, wx1*wy0, wx0*wy1, wx1*wy1 };
#pragma unroll
            for (int c = 0; c < 4; ++c) {
                int xi = xs[c], yi = ys[c];
                if (xi >= 0 && xi < HPX && yi >= 0 && yi < HPX) {
                    float wgt = wt[c];
                    if (use_tex_t) {
                        const float4 a = *(const float4*)(tex_t +
                            (((size_t)n3 * HWSZ + (size_t)yi * HPX + xi) * 32 + g * 4));
                        acc[0] = fmaf(wgt, a.x, acc[0]); acc[1] = fmaf(wgt, a.y, acc[1]);
                        acc[2] = fmaf(wgt, a.z, acc[2]); acc[3] = fmaf(wgt, a.w, acc[3]);
                    } else {
                        size_t base = ((size_t)(n3 * 32 + g * 4)) * HWSZ + (size_t)yi * HPX + xi;
#pragma unroll
                        for (int u = 0; u < 4; ++u)
                            acc[u] = fmaf(wgt, tex_raw[base + (size_t)u * HWSZ], acc[u]);
                    }
                }
            }
        }
#pragma unroll
        for (int u = 0; u < 4; ++u) A[(g*4 + u) * 64 + m] = acc[u] * (1.f / 3.f);
    }

    // ---------- phase 2: per-neighbor point MLP, k sequential ----------
    float pts_acc[4];
#pragma unroll
    for (int u = 0; u < 4; ++u) pts_acc[u] = 0.f;

#pragma unroll 1
    for (int k = 0; k < KNN; ++k) {
        // k.a: build x59 into B rows 64..122 (col = m)
        {
            const int m = lane, g = wv;
            const int q = q0 + m;
            const int id = idxbuf[(size_t)q*4 + k];
            // emb channels g*4..g*4+3
            const float4 ea = *(const float4*)(emb + (size_t)id * 32 + g * 4);
            B[(64 + g*4 + 0)*64 + m] = ea.x; B[(64 + g*4 + 1)*64 + m] = ea.y;
            B[(64 + g*4 + 2)*64 + m] = ea.z; B[(64 + g*4 + 3)*64 + m] = ea.w;

            const float cx = coords[q*3+0], cy = coords[q*3+1], cz = coords[q*3+2];
            const float nx = pts[((size_t)n*PP + id)*3 + 0];
            const float ny = pts[((size_t)n*PP + id)*3 + 1];
            const float nz = pts[((size_t)n*PP + id)*3 + 2];
            float rx = cx - nx, ry = cy - ny, rz = cz - nz;
            float nrm = sqrtf(fmaf(rx, rx, fmaf(ry, ry, rz*rz)));
            float inv = 1.f / fmaxf(nrm, 1e-12f);
            rx *= inv; ry *= inv; rz *= inv;
            // harmonic rows 96..122: wave g handles h in [g*4, g*4+4) ∩ [0,27)
            const int h0 = g * 4;
#pragma unroll
            for (int hh = 0; hh < 4; ++hh) {
                int h = h0 + hh;
                if (h < 27) {
                    float v;
                    if (h < 24) {
                        int base = (h < 12) ? h : (h - 12);
                        float rv = (base >> 2) == 0 ? rx : ((base >> 2) == 1 ? ry : rz);
                        float e = rv * (float)(1 << (base & 3));
                        v = (h < 12) ? sinf(e) : cosf(e);
                    } else {
                        v = (h == 24) ? rx : ((h == 25) ? ry : rz);
                    }
                    B[(96 + h)*64 + m] = v;
                }
            }
        }
        __syncthreads();
        // k.b: p1 59->64 relu, wave g -> j0 = g*8
        {
            float x[59];
#pragma unroll
            for (int i = 0; i < 59; ++i) x[i] = B[(64 + i)*64 + lane];
            float acc[8];
            gemv_tile<59, 64, 8>(x, pw1, pb1, wv * 8, acc);
#pragma unroll
            for (int u = 0; u < 8; ++u) B[(wv*8 + u)*64 + lane] = fmaxf(acc[u], 0.f);
        }
        __syncthreads();
        // k.c: p2 64->32 (no relu), accumulate w_k * h2
        {
            float x[64];
#pragma unroll
            for (int i = 0; i < 64; ++i) x[i] = B[i*64 + lane];
            float acc[4];
            gemv_tile<64, 32, 4>(x, pw2, pb2, wv * 4, acc);
            const int q = q0 + lane;
            float dist = distbuf[(size_t)q*4 + k];
            float wk = (1.0f / dist) / sums[n*4 + k];
#pragma unroll
            for (int u = 0; u < 4; ++u) pts_acc[u] = fmaf(wk, acc[u], pts_acc[u]);
        }
        __syncthreads();
    }
#pragma unroll
    for (int u = 0; u < 4; ++u) A[(32 + wv*4 + u)*64 + lane] = pts_acc[u];
    __syncthreads();

    // ---------- dense stack ----------
    // fw1: 64 -> 128, relu, A -> B ; tile 16, j0 = wv*16
    {
        float x[64];
#pragma unroll
        for (int i = 0; i < 64; ++i) x[i] = A[i*64 + lane];
        float acc[16];
        gemv_tile<64, 128, 16>(x, fw1, fb1, wv * 16, acc);
#pragma unroll
        for (int u = 0; u < 16; ++u) B[(wv*16 + u)*64 + lane] = fmaxf(acc[u], 0.f);
    }
    __syncthreads();
    // fw2: 128 -> 128, relu, B -> A
    {
        float x[128];
#pragma unroll
        for (int i = 0; i < 128; ++i) x[i] = B[i*64 + lane];
        float acc[16];
        gemv_tile<128, 128, 16>(x, fw2, fb2, wv * 16, acc);
#pragma unroll
        for (int u = 0; u < 16; ++u) A[(wv*16 + u)*64 + lane] = fmaxf(acc[u], 0.f);
    }
    __syncthreads();
    // fw3: 128 -> 128, no relu, A -> B
    {
        float x[128];
#pragma unroll
        for (int i = 0; i < 128; ++i) x[i] = A[i*64 + lane];
        float acc[16];
        gemv_tile<128, 128, 16>(x, fw3, fb3, wv * 16, acc);
#pragma unroll
        for (int u = 0; u < 16; ++u) B[(wv*16 + u)*64 + lane] = acc[u];
    }
    __syncthreads();
    // head: density + rgb (rw1 155->64 relu, tile 8)
    {
        float x[155];
#pragma unroll
        for (int i = 0; i < 128; ++i) x[i] = B[i*64 + lane];
        const int q = q0 + lane;
        if (wv == 0) {
            float z = db[0];
#pragma unroll
            for (int i = 0; i < 128; ++i) z = fmaf(x[i], dw[i], z);
            const float cx = coords[q*3+0], cy = coords[q*3+1], cz = coords[q*3+2];
            float selv = (cx > -1.f && cx < 1.f && cy > -1.f && cy < 1.f &&
                          cz > -1.f && cz < 1.f) ? 1.f : 0.f;
            float t10 = 10.f * z;
            float sp = (t10 > 20.f) ? t10 : log1pf(expf(t10));
            float raw = sp * 0.1f * selv;
            out[q] = 1.f - expf(-raw);
        }
        // ray harmonic into x[128..154]
        float dx = dirs[q*3+0], dy = dirs[q*3+1], dz = dirs[q*3+2];
        float dn = sqrtf(fmaf(dx, dx, fmaf(dy, dy, dz*dz)));
        float inv = 1.f / fmaxf(dn, 1e-12f);
        dx *= inv; dy *= inv; dz *= inv;
#pragma unroll
        for (int c3 = 0; c3 < 3; ++c3) {
            float rv = (c3 == 0) ? dx : ((c3 == 1) ? dy : dz);
            float f = 1.f;
#pragma unroll
            for (int fr = 0; fr < 4; ++fr) {
                float e = rv * f;
                x[128 + c3*4 + fr] = sinf(e);
                x[140 + c3*4 + fr] = cosf(e);
                f *= 2.f;
            }
        }
        x[152] = dx; x[153] = dy; x[154] = dz;
        float acc[8];
        gemv_tile<155, 64, 8>(x, rw1, rb1, wv * 8, acc);
#pragma unroll
        for (int u = 0; u < 8; ++u) A[(wv*8 + u)*64 + lane] = fmaxf(acc[u], 0.f);
    }
    __syncthreads();
    // rw2: 64 -> 32, sigmoid on first 3; tile 4
    {
        float x[64];
#pragma unroll
        for (int i = 0; i < 64; ++i) x[i] = A[i*64 + lane];
        float acc[4];
        gemv_tile<64, 32, 4>(x, rw2, rb2, wv * 4, acc);
        const int q = q0 + lane;
#pragma unroll
        for (int u = 0; u < 4; ++u) {
            int j = wv*4 + u;
            float v = acc[u];
            if (j < 3) v = 1.002f * (1.f / (1.f + expf(-v))) - 0.001f;
            out[OUT_RGB_OFF + (size_t)q*32 + j] = v;
        }
    }
}

// ------------------------------------------------------------------
extern "C" void kernel_launch(void* const* d_in, const int* in_sizes, int n_in,
                              void* d_out, int out_size, void* d_ws, size_t ws_size,
                              hipStream_t stream) {
    (void)in_sizes; (void)n_in; (void)out_size;
    const float* coords = (const float*)d_in[0];
    const float* dirs   = (const float*)d_in[1];
    const float* pts    = (const float*)d_in[2];
    const float* tex    = (const float*)d_in[3];
    const float* emb    = (const float*)d_in[4];
    const float* pw1 = (const float*)d_in[5];  const float* pb1 = (const float*)d_in[6];
    const float* pw2 = (const float*)d_in[7];  const float* pb2 = (const float*)d_in[8];
    const float* fw1 = (const float*)d_in[9];  const float* fb1 = (const float*)d_in[10];
    const float* fw2 = (const float*)d_in[11]; const float* fb2 = (const float*)d_in[12];
    const float* fw3 = (const float*)d_in[13]; const float* fb3 = (const float*)d_in[14];
    const float* dw  = (const float*)d_in[15]; const float* db  = (const float*)d_in[16];
    const float* rw1 = (const float*)d_in[17]; const float* rb1 = (const float*)d_in[18];
    const float* rw2 = (const float*)d_in[19]; const float* rb2 = (const float*)d_in[20];

    float* out    = (float*)d_out;
    int*   wsidx  = (int*)d_ws;
    float* wssums = (float*)((char*)d_ws + WS_SUMS_OFF);
    float* wstex  = (float*)((char*)d_ws + WS_TEX_OFF);

    const size_t need_tex = WS_TEX_OFF + (size_t)6 * HWSZ * 32 * 4;
    const int use_t = (ws_size >= need_tex) ? 1 : 0;

    if (use_t) k_transpose<<<6 * 256, 256, 0, stream>>>(tex, wstex);
    k_knn<<<NQ / 16, 256, 0, stream>>>(coords, pts, out + OUT_DIST_OFF, wsidx);
    k_sums<<<8, 1024, 0, stream>>>(out + OUT_DIST_OFF, wssums);
    k_main<<<NQ / 64, 512, 0, stream>>>(coords, dirs, pts, tex, wstex, emb,
                                        pw1, pb1, pw2, pb2,
                                        fw1, fb1, fw2, fb2, fw3, fb3,
                                        dw, db, rw1, rb1, rw2, rb2,
                                        wsidx, out + OUT_DIST_OFF, wssums, out, use_t);
}

// Round 3
// 428.326 us; speedup vs baseline: 1.3648x; 1.1401x over previous
//
#include <hip/hip_runtime.h>
#include <float.h>
#include <math.h>

#define NB 2
#define MQ 16384
#define NQ (NB*MQ)          // 32768 queries
#define PP 5023
#define KNN 4
#define HPX 256
#define HWSZ (HPX*HPX)      // 65536

// output layout (floats): densities[NQ], rgb[NQ*32], dist[NQ*4]
#define OUT_RGB_OFF  ((size_t)NQ)
#define OUT_DIST_OFF ((size_t)NQ + (size_t)NQ*32)

// workspace layout (bytes)
#define WS_SUMS_OFF ((size_t)NQ*KNN*4)   // after idx region (NQ*4 ints)
#define WS_TEX_OFF  ((size_t)1<<20)

// ------------------------------------------------------------------
// texture transpose: [n3][32][HW] -> [n3][HW][32]
__global__ __launch_bounds__(256) void k_transpose(const float* __restrict__ src,
                                                   float* __restrict__ dst) {
    const int tid = threadIdx.x;
    const int b = blockIdx.x;            // 6*256 blocks
    const int n3 = b >> 8;
    const int hw = ((b & 255) << 8) + tid;
    const float* s = src + (size_t)n3 * 32 * HWSZ + hw;
    float v[32];
#pragma unroll
    for (int c = 0; c < 32; ++c) v[c] = s[(size_t)c * HWSZ];
    float4* d = (float4*)(dst + ((size_t)n3 * HWSZ + hw) * 32);
#pragma unroll
    for (int c = 0; c < 8; ++c) d[c] = make_float4(v[4*c], v[4*c+1], v[4*c+2], v[4*c+3]);
}

// ------------------------------------------------------------------
// KNN: 16 lanes per query, LDS-staged point chunks, branchless insert
#define KCH 1024
__global__ __launch_bounds__(256) void k_knn(const float* __restrict__ coords,
                                             const float* __restrict__ pts,
                                             float* __restrict__ odist,
                                             int* __restrict__ oidx) {
    __shared__ float4 sp[KCH];
    const int tid = threadIdx.x;
    const int l = tid & 15;
    const int q = blockIdx.x * 16 + (tid >> 4);   // 2048 blocks
    const int n = q >> 14;
    const float cx = coords[q*3+0], cy = coords[q*3+1], cz = coords[q*3+2];
    const float cc = fmaf(cx, cx, fmaf(cy, cy, cz*cz));

    float bd0 = FLT_MAX, bd1 = FLT_MAX, bd2 = FLT_MAX, bd3 = FLT_MAX;
    int   bi0 = 0x7fffffff, bi1 = 0x7fffffff, bi2 = 0x7fffffff, bi3 = 0x7fffffff;

    const float* pb = pts + (size_t)n * PP * 3;
#pragma unroll 1
    for (int c0 = 0; c0 < PP; c0 += KCH) {
        const int cnt = (PP - c0 < KCH) ? (PP - c0) : KCH;
        __syncthreads();
        for (int j = tid; j < cnt; j += 256) {
            const float* p3 = pb + (size_t)(c0 + j) * 3;
            float px = p3[0], py = p3[1], pz = p3[2];
            sp[j] = make_float4(px, py, pz, fmaf(px, px, fmaf(py, py, pz*pz)));
        }
        __syncthreads();
#pragma unroll 4
        for (int j = l; j < cnt; j += 16) {
            float4 P = sp[j];
            float dt = fmaf(cx, P.x, fmaf(cy, P.y, cz * P.z));
            float dd = fmaf(-2.0f, dt, cc + P.w);
            int p = c0 + j;
            bool lt3 = dd < bd3, lt2 = dd < bd2, lt1 = dd < bd1, lt0 = dd < bd0;
            bd3 = lt3 ? (lt2 ? bd2 : dd) : bd3;  bi3 = lt3 ? (lt2 ? bi2 : p) : bi3;
            bd2 = lt2 ? (lt1 ? bd1 : dd) : bd2;  bi2 = lt2 ? (lt1 ? bi1 : p) : bi2;
            bd1 = lt1 ? (lt0 ? bd0 : dd) : bd1;  bi1 = lt1 ? (lt0 ? bi0 : p) : bi1;
            bd0 = lt0 ? dd : bd0;                bi0 = lt0 ? p : bi0;
        }
    }

    float bd[4] = { bd0, bd1, bd2, bd3 };
    int   bi[4] = { bi0, bi1, bi2, bi3 };
    // butterfly merge of sorted 4-lists within the 16-lane group (tie-break on index)
#pragma unroll
    for (int mask = 1; mask < 16; mask <<= 1) {
        float od[4]; int oi[4];
#pragma unroll
        for (int j = 0; j < 4; ++j) { od[j] = __shfl_xor(bd[j], mask); oi[j] = __shfl_xor(bi[j], mask); }
        float e[4]; int ei[4];
#pragma unroll
        for (int j = 0; j < 4; ++j) {
            float ad = bd[j], xd = od[3-j];
            int   ai = bi[j], xi = oi[3-j];
            bool ta = (ad < xd) || (ad == xd && ai < xi);
            e[j] = ta ? ad : xd; ei[j] = ta ? ai : xi;
        }
#define CE(a,b) { bool sw = (e[b] < e[a]) || (e[b] == e[a] && ei[b] < ei[a]); \
                  if (sw) { float td=e[a]; e[a]=e[b]; e[b]=td; int ti=ei[a]; ei[a]=ei[b]; ei[b]=ti; } }
        CE(0,2) CE(1,3) CE(0,1) CE(2,3)
#undef CE
#pragma unroll
        for (int j = 0; j < 4; ++j) { bd[j] = e[j]; bi[j] = ei[j]; }
    }

    if (l == 0) {
        *(float4*)(odist + (size_t)q*4) = make_float4(bd[0], bd[1], bd[2], bd[3]);
        *(int4*)(oidx + (size_t)q*4)    = make_int4(bi[0], bi[1], bi[2], bi[3]);
    }
}

// ------------------------------------------------------------------
// per-(n,k) sum over m of 1/dist (deterministic)
__global__ __launch_bounds__(1024) void k_sums(const float* __restrict__ dist,
                                               float* __restrict__ sums) {
    const int b = blockIdx.x;            // n*4+k, 8 blocks
    const int n = b >> 2, k = b & 3;
    float s = 0.f;
    for (int m = threadIdx.x; m < MQ; m += 1024)
        s += 1.0f / dist[((size_t)n * MQ + m) * 4 + k];
    __shared__ float red[1024];
    red[threadIdx.x] = s;
    __syncthreads();
    for (int off = 512; off > 0; off >>= 1) {
        if (threadIdx.x < off) red[threadIdx.x] += red[threadIdx.x + off];
        __syncthreads();
    }
    if (threadIdx.x == 0) sums[b] = red[0];
}

// ------------------------------------------------------------------
// streaming gemv: activations read from LDS (column = lane), weights via
// wave-uniform s_load. NO per-lane x[] register array -> no scratch spill.
template<int DIN, int DOUT, int TILE>
__device__ __forceinline__ void gemv_lds(const float* __restrict__ X,  // LDS, [DIN][64]
                                         int lane,
                                         const float* __restrict__ W,
                                         const float* __restrict__ bias,
                                         int j0, float (&acc)[TILE]) {
#pragma unroll
    for (int u = 0; u < TILE; ++u) acc[u] = bias[j0 + u];
#pragma unroll
    for (int i = 0; i < DIN; ++i) {
        const float xv = X[i * 64 + lane];
        const float* wr = W + i * DOUT + j0;
#pragma unroll
        for (int u = 0; u < TILE; ++u) acc[u] = fmaf(xv, wr[u], acc[u]);
    }
}

// ------------------------------------------------------------------
// main fused kernel v3: block = 64 queries, 8 waves, activations streamed
// from LDS inside every gemv (no big register arrays, no spill)
__global__ __launch_bounds__(512, 4) void k_main(
    const float* __restrict__ coords, const float* __restrict__ dirs,
    const float* __restrict__ pts, const float* __restrict__ tex_raw,
    const float* __restrict__ tex_t, const float* __restrict__ emb,
    const float* __restrict__ pw1, const float* __restrict__ pb1,
    const float* __restrict__ pw2, const float* __restrict__ pb2,
    const float* __restrict__ fw1, const float* __restrict__ fb1,
    const float* __restrict__ fw2, const float* __restrict__ fb2,
    const float* __restrict__ fw3, const float* __restrict__ fb3,
    const float* __restrict__ dw,  const float* __restrict__ db,
    const float* __restrict__ rw1, const float* __restrict__ rb1,
    const float* __restrict__ rw2, const float* __restrict__ rb2,
    const int* __restrict__ idxbuf, const float* __restrict__ distbuf,
    const float* __restrict__ sums, float* __restrict__ out, int use_tex_t)
{
    __shared__ float A[128 * 64];
    __shared__ float B[128 * 64];
    const int tid  = threadIdx.x;
    const int lane = tid & 63;
    const int wv   = __builtin_amdgcn_readfirstlane(tid >> 6);   // 0..7
    const int q0   = blockIdx.x * 64;
    const int n    = q0 >> 14;

    // ---------- phase 1: triplane sampling -> A rows 0..31 (mean/3) ----------
    {
        const int m = lane, g = wv;   // g: channel group of 4
        const int q = q0 + m;
        const float cx = coords[q*3+0], cy = coords[q*3+1], cz = coords[q*3+2];
        float acc[4];
#pragma unroll
        for (int u = 0; u < 4; ++u) acc[u] = 0.f;
#pragma unroll
        for (int pl = 0; pl < 3; ++pl) {
            float gx = (pl == 2) ? cz : cx;
            float gy = (pl == 0) ? cy : ((pl == 1) ? cz : cx);
            float x = (gx + 1.f) * 128.f - 0.5f;
            float y = (gy + 1.f) * 128.f - 0.5f;
            float x0f = floorf(x), y0f = floorf(y);
            float wx1 = x - x0f, wy1 = y - y0f;
            float wx0 = 1.f - wx1, wy0 = 1.f - wy1;
            int x0 = (int)x0f, y0 = (int)y0f;
            int n3 = n * 3 + pl;
            int  xs[4] = { x0, x0+1, x0,   x0+1 };
            int  ys[4] = { y0, y0,   y0+1, y0+1 };
            float wt[4] = { wx0*wy0, wx1*wy0, wx0*wy1, wx1*wy1 };
#pragma unroll
            for (int c = 0; c < 4; ++c) {
                int xi = xs[c], yi = ys[c];
                if (xi >= 0 && xi < HPX && yi >= 0 && yi < HPX) {
                    float wgt = wt[c];
                    if (use_tex_t) {
                        const float4 a = *(const float4*)(tex_t +
                            (((size_t)n3 * HWSZ + (size_t)yi * HPX + xi) * 32 + g * 4));
                        acc[0] = fmaf(wgt, a.x, acc[0]); acc[1] = fmaf(wgt, a.y, acc[1]);
                        acc[2] = fmaf(wgt, a.z, acc[2]); acc[3] = fmaf(wgt, a.w, acc[3]);
                    } else {
                        size_t base = ((size_t)(n3 * 32 + g * 4)) * HWSZ + (size_t)yi * HPX + xi;
#pragma unroll
                        for (int u = 0; u < 4; ++u)
                            acc[u] = fmaf(wgt, tex_raw[base + (size_t)u * HWSZ], acc[u]);
                    }
                }
            }
        }
#pragma unroll
        for (int u = 0; u < 4; ++u) A[(g*4 + u) * 64 + m] = acc[u] * (1.f / 3.f);
    }

    // ---------- phase 2: per-neighbor point MLP, k sequential ----------
    float pts_acc[4];
#pragma unroll
    for (int u = 0; u < 4; ++u) pts_acc[u] = 0.f;

#pragma unroll 1
    for (int k = 0; k < KNN; ++k) {
        // k.a: build x59 into B rows 64..122 (col = m)
        {
            const int m = lane, g = wv;
            const int q = q0 + m;
            const int id = idxbuf[(size_t)q*4 + k];
            const float4 ea = *(const float4*)(emb + (size_t)id * 32 + g * 4);
            B[(64 + g*4 + 0)*64 + m] = ea.x; B[(64 + g*4 + 1)*64 + m] = ea.y;
            B[(64 + g*4 + 2)*64 + m] = ea.z; B[(64 + g*4 + 3)*64 + m] = ea.w;

            const float cx = coords[q*3+0], cy = coords[q*3+1], cz = coords[q*3+2];
            const float nx = pts[((size_t)n*PP + id)*3 + 0];
            const float ny = pts[((size_t)n*PP + id)*3 + 1];
            const float nz = pts[((size_t)n*PP + id)*3 + 2];
            float rx = cx - nx, ry = cy - ny, rz = cz - nz;
            float nrm = sqrtf(fmaf(rx, rx, fmaf(ry, ry, rz*rz)));
            float inv = 1.f / fmaxf(nrm, 1e-12f);
            rx *= inv; ry *= inv; rz *= inv;
            // harmonic rows 96..122: wave g handles h in [g*4, g*4+4) ∩ [0,27)
            const int h0 = g * 4;
#pragma unroll
            for (int hh = 0; hh < 4; ++hh) {
                int h = h0 + hh;
                if (h < 27) {
                    float v;
                    if (h < 24) {
                        int base = (h < 12) ? h : (h - 12);
                        float rv = (base >> 2) == 0 ? rx : ((base >> 2) == 1 ? ry : rz);
                        float e = rv * (float)(1 << (base & 3));
                        v = (h < 12) ? sinf(e) : cosf(e);
                    } else {
                        v = (h == 24) ? rx : ((h == 25) ? ry : rz);
                    }
                    B[(96 + h)*64 + m] = v;
                }
            }
        }
        __syncthreads();
        // k.b: p1 59->64 relu, wave g -> j0 = g*8
        {
            float acc[8];
            gemv_lds<59, 64, 8>(B + 64*64, lane, pw1, pb1, wv * 8, acc);
            __syncthreads();   // before overwriting rows 0..63 read last iter? (reads were rows 64.., safe) -- keeps write ordering vs k.c reads
#pragma unroll
            for (int u = 0; u < 8; ++u) B[(wv*8 + u)*64 + lane] = fmaxf(acc[u], 0.f);
        }
        __syncthreads();
        // k.c: p2 64->32 (no relu), accumulate w_k * h2
        {
            float acc[4];
            gemv_lds<64, 32, 4>(B, lane, pw2, pb2, wv * 4, acc);
            const int q = q0 + lane;
            float dist = distbuf[(size_t)q*4 + k];
            float wk = (1.0f / dist) / sums[n*4 + k];
#pragma unroll
            for (int u = 0; u < 4; ++u) pts_acc[u] = fmaf(wk, acc[u], pts_acc[u]);
        }
        __syncthreads();
    }
#pragma unroll
    for (int u = 0; u < 4; ++u) A[(32 + wv*4 + u)*64 + lane] = pts_acc[u];
    __syncthreads();

    // ---------- dense stack ----------
    // fw1: 64 -> 128, relu, A -> B ; tile 16, j0 = wv*16
    {
        float acc[16];
        gemv_lds<64, 128, 16>(A, lane, fw1, fb1, wv * 16, acc);
#pragma unroll
        for (int u = 0; u < 16; ++u) B[(wv*16 + u)*64 + lane] = fmaxf(acc[u], 0.f);
    }
    __syncthreads();
    // fw2: 128 -> 128, relu, B -> A
    {
        float acc[16];
        gemv_lds<128, 128, 16>(B, lane, fw2, fb2, wv * 16, acc);
#pragma unroll
        for (int u = 0; u < 16; ++u) A[(wv*16 + u)*64 + lane] = fmaxf(acc[u], 0.f);
    }
    __syncthreads();
    // fw3: 128 -> 128, no relu, A -> B
    {
        float acc[16];
        gemv_lds<128, 128, 16>(A, lane, fw3, fb3, wv * 16, acc);
#pragma unroll
        for (int u = 0; u < 16; ++u) B[(wv*16 + u)*64 + lane] = acc[u];
    }
    __syncthreads();
    // head: density + rgb (rw1 155->64 relu, tile 8); feat in B rows 0..127
    {
        const int q = q0 + lane;
        if (wv == 0) {
            float z = db[0];
#pragma unroll
            for (int i = 0; i < 128; ++i) z = fmaf(B[i*64 + lane], dw[i], z);
            const float cx = coords[q*3+0], cy = coords[q*3+1], cz = coords[q*3+2];
            float selv = (cx > -1.f && cx < 1.f && cy > -1.f && cy < 1.f &&
                          cz > -1.f && cz < 1.f) ? 1.f : 0.f;
            float t10 = 10.f * z;
            float sp = (t10 > 20.f) ? t10 : log1pf(expf(t10));
            float raw = sp * 0.1f * selv;
            out[q] = 1.f - expf(-raw);
        }
        // ray harmonic (27 values in registers)
        float dx = dirs[q*3+0], dy = dirs[q*3+1], dz = dirs[q*3+2];
        float dn = sqrtf(fmaf(dx, dx, fmaf(dy, dy, dz*dz)));
        float inv = 1.f / fmaxf(dn, 1e-12f);
        dx *= inv; dy *= inv; dz *= inv;
        float hv[27];
#pragma unroll
        for (int c3 = 0; c3 < 3; ++c3) {
            float rv = (c3 == 0) ? dx : ((c3 == 1) ? dy : dz);
            float f = 1.f;
#pragma unroll
            for (int fr = 0; fr < 4; ++fr) {
                float e = rv * f;
                hv[c3*4 + fr] = sinf(e);
                hv[12 + c3*4 + fr] = cosf(e);
                f *= 2.f;
            }
        }
        hv[24] = dx; hv[25] = dy; hv[26] = dz;
        const int j0 = wv * 8;
        float acc[8];
        gemv_lds<128, 64, 8>(B, lane, rw1, rb1, j0, acc);   // first 128 dims
#pragma unroll
        for (int h = 0; h < 27; ++h) {                      // remaining 27 dims
            const float* wr = rw1 + (128 + h) * 64 + j0;
#pragma unroll
            for (int u = 0; u < 8; ++u) acc[u] = fmaf(hv[h], wr[u], acc[u]);
        }
        __syncthreads();   // ensure all reads of B done before A overwritten below? A distinct; keep order vs density reads of B
#pragma unroll
        for (int u = 0; u < 8; ++u) A[(j0 + u)*64 + lane] = fmaxf(acc[u], 0.f);
    }
    __syncthreads();
    // rw2: 64 -> 32, sigmoid on first 3; tile 4
    {
        float acc[4];
        gemv_lds<64, 32, 4>(A, lane, rw2, rb2, wv * 4, acc);
        const int q = q0 + lane;
#pragma unroll
        for (int u = 0; u < 4; ++u) {
            int j = wv*4 + u;
            float v = acc[u];
            if (j < 3) v = 1.002f * (1.f / (1.f + expf(-v))) - 0.001f;
            out[OUT_RGB_OFF + (size_t)q*32 + j] = v;
        }
    }
}

// ------------------------------------------------------------------
extern "C" void kernel_launch(void* const* d_in, const int* in_sizes, int n_in,
                              void* d_out, int out_size, void* d_ws, size_t ws_size,
                              hipStream_t stream) {
    (void)in_sizes; (void)n_in; (void)out_size;
    const float* coords = (const float*)d_in[0];
    const float* dirs   = (const float*)d_in[1];
    const float* pts    = (const float*)d_in[2];
    const float* tex    = (const float*)d_in[3];
    const float* emb    = (const float*)d_in[4];
    const float* pw1 = (const float*)d_in[5];  const float* pb1 = (const float*)d_in[6];
    const float* pw2 = (const float*)d_in[7];  const float* pb2 = (const float*)d_in[8];
    const float* fw1 = (const float*)d_in[9];  const float* fb1 = (const float*)d_in[10];
    const float* fw2 = (const float*)d_in[11]; const float* fb2 = (const float*)d_in[12];
    const float* fw3 = (const float*)d_in[13]; const float* fb3 = (const float*)d_in[14];
    const float* dw  = (const float*)d_in[15]; const float* db  = (const float*)d_in[16];
    const float* rw1 = (const float*)d_in[17]; const float* rb1 = (const float*)d_in[18];
    const float* rw2 = (const float*)d_in[19]; const float* rb2 = (const float*)d_in[20];

    float* out    = (float*)d_out;
    int*   wsidx  = (int*)d_ws;
    float* wssums = (float*)((char*)d_ws + WS_SUMS_OFF);
    float* wstex  = (float*)((char*)d_ws + WS_TEX_OFF);

    const size_t need_tex = WS_TEX_OFF + (size_t)6 * HWSZ * 32 * 4;
    const int use_t = (ws_size >= need_tex) ? 1 : 0;

    if (use_t) k_transpose<<<6 * 256, 256, 0, stream>>>(tex, wstex);
    k_knn<<<NQ / 16, 256, 0, stream>>>(coords, pts, out + OUT_DIST_OFF, wsidx);
    k_sums<<<8, 1024, 0, stream>>>(out + OUT_DIST_OFF, wssums);
    k_main<<<NQ / 64, 512, 0, stream>>>(coords, dirs, pts, tex, wstex, emb,
                                        pw1, pb1, pw2, pb2,
                                        fw1, fb1, fw2, fb2, fw3, fb3,
                                        dw, db, rw1, rb1, rw2, rb2,
                                        wsidx, out + OUT_DIST_OFF, wssums, out, use_t);
}